// Round 1
// 260.010 us; speedup vs baseline: 1.0052x; 1.0052x over previous
//
#include <hip/hip_runtime.h>
#include <math.h>

// ContextCluster, fp32, MI355X gfx950 — round 10.
// R9 analysis: cc_main FETCH=214MB (2x logical) because blk&7=f2 split each
// 64B x-line across 2 XCDs and heg re-readers were 1024 blocks apart (no L2
// reuse). cc_proj was latency-bound: grid 1024 = exactly 4 blocks/CU, two
// barriers per chunk, both pipes <30%.
// R10: (a) cc_main decode f1=blk&7 -> XCD k reads only x rows f1==k
//      (3.1MB slice, L2-resident; heg re-reads 8 blocks apart in XCD order);
//      (b) inner-loop x reads as one ds_read_b128 (px=tp*4..+3, was 4x b32);
//      (c) cc_proj: px-tile 32, 2048 blocks = 8 blocks/CU (100% occ, LDS
//      16.8KB, VGPR<=64), thread tile 6oc x 2px, float2 x reads, XCD-matched
//      to K1 writer via f1=blk&7. Numerics identical to R9 (same k order).

#define TPB 256

__global__ __launch_bounds__(TPB, 4)
void cc_main(const float* __restrict__ x,
             const float* __restrict__ Wf, const float* __restrict__ bf,
             const float* __restrict__ Wv, const float* __restrict__ bv,
             const float* __restrict__ salpha, const float* __restrict__ sbeta,
             float* __restrict__ disp)
{
    // GEMM: Wt = smem[0..4096) [32k][128ch], Xt = smem[4096..6144) [32k][64px]
    // Cluster: fvbuf = smem[0..8320) [128ch][65]
    __shared__ __align__(16) float smem[8320];
    __shared__ float cfs[2][132], cvs[2][132], swb[2][256], aggs[2][132];

    const int t    = threadIdx.x;
    const int lane = t & 63;
    const int wid  = __builtin_amdgcn_readfirstlane(t >> 6);  // 0..3
    const int tc   = t >> 4;          // 0..15: ch-group (8 ch)
    const int tp   = t & 15;          // px-group (4 consecutive px)
    const int blk  = blockIdx.x;
    // XCD-partitioned decode: XCD = blk&7 = f1 -> each XCD touches only its
    // own 3.1 MB x row-slice; heg (re-reader of same 24KB chunk) is 8 blocks
    // apart in XCD-local dispatch order -> L2-resident reuse.
    const int f1   = blk & 7;
    const int f2   = (blk >> 3) & 7;
    const int heg  = (blk >> 6) & 3;  // head-pair 0..3
    const int bb   = blk >> 8;        // batch 0..15
    const int fold = f1*8 + f2;

    const float* xb = x + (size_t)bb*96*4096 + (size_t)(f1*8)*64 + f2*8;

    // ---- accumulators (8 ch x 4 px), bias-init ----
    float acc[8][4];
    {
        const float* bsrc = (tc < 8) ? (bf + heg*64 + tc*8)
                                     : (bv + heg*64 + (tc-8)*8);
        float4 b0 = *(const float4*)bsrc;
        float4 b1 = *(const float4*)(bsrc + 4);
        #pragma unroll
        for (int i = 0; i < 4; ++i) {
            acc[0][i]=b0.x; acc[1][i]=b0.y; acc[2][i]=b0.z; acc[3][i]=b0.w;
            acc[4][i]=b1.x; acc[5][i]=b1.y; acc[6][i]=b1.z; acc[7][i]=b1.w;
        }
    }

    // ---- staging decode (t-constant) ----
    // X: 512 float4/chunk, 2/thread
    int xoff[2], xdst[2];
    #pragma unroll
    for (int i = 0; i < 2; ++i) {
        int fl = i*256 + t;
        int kl = fl >> 4, sg = fl & 15;
        xoff[i] = kl*4096 + (sg >> 1)*64 + (sg & 1)*4;
        xdst[i] = 4096 + kl*64 + sg*4;
    }
    // W: 1024 float4/chunk, 4/thread; rr = fl&127 -> 64 consecutive rr per
    // store instr -> 2 lanes/bank (conflict-free). kq wave-uniform.
    int wdst[4];
    const float* wptr[4];
    #pragma unroll
    for (int i = 0; i < 4; ++i) {
        int fl = i*256 + t;
        int rr = fl & 127, kq = fl >> 7;
        wptr[i] = ((rr < 64) ? (Wf + (size_t)(heg*64 + rr)*96)
                             : (Wv + (size_t)(heg*64 + rr - 64)*96)) + kq*4;
        wdst[i] = (kq*4)*128 + rr;
    }

    float4 pxr[2], pwr[4];
    #pragma unroll
    for (int i = 0; i < 2; ++i) pxr[i] = *(const float4*)(xb + xoff[i]);
    #pragma unroll
    for (int i = 0; i < 4; ++i) pwr[i] = *(const float4*)(wptr[i]);
    #pragma unroll
    for (int i = 0; i < 2; ++i) *(float4*)&smem[xdst[i]] = pxr[i];
    #pragma unroll
    for (int i = 0; i < 4; ++i) {
        smem[wdst[i]      ] = pwr[i].x;
        smem[wdst[i] + 128] = pwr[i].y;
        smem[wdst[i] + 256] = pwr[i].z;
        smem[wdst[i] + 384] = pwr[i].w;
    }
    __syncthreads();                  // chunk0 ready

    for (int kc = 0; ; ) {
        if (kc < 64) {                // prefetch next chunk into regs
            #pragma unroll
            for (int i = 0; i < 2; ++i)
                pxr[i] = *(const float4*)(xb + (kc+32)*4096 + xoff[i]);
            #pragma unroll
            for (int i = 0; i < 4; ++i)
                pwr[i] = *(const float4*)(wptr[i] + kc + 32);
        }
        // ---- GEMM chunk: 32 k, 32 FMA/thread/k, 3 LDS b128/thread/k ----
        #pragma unroll 4
        for (int k = 0; k < 32; ++k) {
            float4 wa  = *(const float4*)&smem[k*128 + tc*8];
            float4 wb4 = *(const float4*)&smem[k*128 + tc*8 + 4];
            float4 xq  = *(const float4*)&smem[4096 + k*64 + tp*4];
            float xv[4] = {xq.x, xq.y, xq.z, xq.w};
            #pragma unroll
            for (int i = 0; i < 4; ++i) {
                acc[0][i] = fmaf(wa.x,  xv[i], acc[0][i]);
                acc[1][i] = fmaf(wa.y,  xv[i], acc[1][i]);
                acc[2][i] = fmaf(wa.z,  xv[i], acc[2][i]);
                acc[3][i] = fmaf(wa.w,  xv[i], acc[3][i]);
                acc[4][i] = fmaf(wb4.x, xv[i], acc[4][i]);
                acc[5][i] = fmaf(wb4.y, xv[i], acc[5][i]);
                acc[6][i] = fmaf(wb4.z, xv[i], acc[6][i]);
                acc[7][i] = fmaf(wb4.w, xv[i], acc[7][i]);
            }
        }
        if (kc == 64) break;
        __syncthreads();              // chunk consumed
        #pragma unroll
        for (int i = 0; i < 2; ++i) *(float4*)&smem[xdst[i]] = pxr[i];
        #pragma unroll
        for (int i = 0; i < 4; ++i) {
            smem[wdst[i]      ] = pwr[i].x;
            smem[wdst[i] + 128] = pwr[i].y;
            smem[wdst[i] + 256] = pwr[i].z;
            smem[wdst[i] + 384] = pwr[i].w;
        }
        __syncthreads();              // next chunk ready
        kc += 32;
    }

    // ---- cluster: dump conv result, waves 0/1 handle heads he=wid ----
    const float alpha = salpha[0], beta = sbeta[0];
    __syncthreads();                  // GEMM reads of smem done
    #pragma unroll
    for (int j = 0; j < 8; ++j)
        #pragma unroll
        for (int i2 = 0; i2 < 4; ++i2)
            smem[(tc*8 + j)*65 + tp*4 + i2] = acc[j][i2];
    __syncthreads();

    if (wid < 2) {
        const int he = wid, slot = he;
        // pool: lane -> (m = lane>>4, c0 = (lane&15)*2), 2 centers each
        {
            int m = lane >> 4, c0 = (lane & 15)*2;
            int pw = m >> 1, ph = m & 1;
            #pragma unroll
            for (int cc = 0; cc < 2; ++cc) {
                int c = c0 + cc;
                float mf = -3.402823466e38f, mv = -3.402823466e38f;
                #pragma unroll
                for (int a = 0; a < 4; ++a)
                    #pragma unroll
                    for (int b2 = 0; b2 < 4; ++b2) {
                        int n = (pw*4 + a)*8 + ph*4 + b2;
                        mf = fmaxf(mf, smem[(he*32 + c)*65 + n]);
                        mv = fmaxf(mv, smem[(64 + he*32 + c)*65 + n]);
                    }
                cfs[slot][m*33 + c] = mf;
                cvs[slot][m*33 + c] = mv;
            }
        }
        // sims (lane = n)
        float d0=0,d1=0,d2=0,d3=0,pn=0,cn0=0,cn1=0,cn2=0,cn3=0;
        #pragma unroll 8
        for (int c = 0; c < 32; ++c) {
            float fv = smem[(he*32 + c)*65 + lane];
            float m0 = cfs[slot][c], m1 = cfs[slot][33+c];
            float m2 = cfs[slot][66+c], m3 = cfs[slot][99+c];
            d0 = fmaf(m0, fv, d0); d1 = fmaf(m1, fv, d1);
            d2 = fmaf(m2, fv, d2); d3 = fmaf(m3, fv, d3);
            pn = fmaf(fv, fv, pn);
            cn0 = fmaf(m0, m0, cn0); cn1 = fmaf(m1, m1, cn1);
            cn2 = fmaf(m2, m2, cn2); cn3 = fmaf(m3, m3, cn3);
        }
        float ip = 1.f / fmaxf(sqrtf(pn), 1e-12f);
        float z0 = beta + alpha*(d0*(1.f/fmaxf(sqrtf(cn0),1e-12f))*ip);
        float z1 = beta + alpha*(d1*(1.f/fmaxf(sqrtf(cn1),1e-12f))*ip);
        float z2 = beta + alpha*(d2*(1.f/fmaxf(sqrtf(cn2),1e-12f))*ip);
        float z3 = beta + alpha*(d3*(1.f/fmaxf(sqrtf(cn3),1e-12f))*ip);
        float s0 = 1.f/(1.f + expf(-z0));
        float s1 = 1.f/(1.f + expf(-z1));
        float s2 = 1.f/(1.f + expf(-z2));
        float s3 = 1.f/(1.f + expf(-z3));
        int bi = 0; float bvv = s0;   // first-max tie-break
        if (s1 > bvv) { bvv = s1; bi = 1; }
        if (s2 > bvv) { bvv = s2; bi = 2; }
        if (s3 > bvv) { bvv = s3; bi = 3; }
        int cnt0 = __popcll(__ballot(bi == 0));
        int cnt1 = __popcll(__ballot(bi == 1));
        int cnt2 = __popcll(__ballot(bi == 2));
        int cnt3 = __popcll(__ballot(bi == 3));
        swb[slot][lane]       = (bi==0) ? bvv : 0.f;
        swb[slot][64 + lane]  = (bi==1) ? bvv : 0.f;
        swb[slot][128 + lane] = (bi==2) ? bvv : 0.f;
        swb[slot][192 + lane] = (bi==3) ? bvv : 0.f;
        // agg: 2 iters, lane -> (m = it*2 + lane>>5, c = lane&31)
        #pragma unroll
        for (int it = 0; it < 2; ++it) {
            int m = it*2 + (lane >> 5);
            int c = lane & 31;
            float s = 0.f;
            #pragma unroll 8
            for (int n2 = 0; n2 < 64; ++n2)
                s = fmaf(smem[(64 + he*32 + c)*65 + n2],
                         swb[slot][m*64 + n2], s);
            int cm = (m==0) ? cnt0 : (m==1) ? cnt1 : (m==2) ? cnt2 : cnt3;
            aggs[slot][m*33 + c] = (s + cvs[slot][m*33 + c]) / (float)(cm + 1);
        }
        // dispatch -> disp[ch][p'']
        const int e32 = (heg*2 + he)*32;
        const size_t obase = (size_t)bb*4096 + (size_t)fold*64 + lane;
        #pragma unroll 4
        for (int c = 0; c < 32; ++c)
            disp[(size_t)(e32 + c)*65536 + obase] = aggs[slot][bi*33 + c] * bvv;
    }
}

// K2: C[96][p''] = Wp[96][256] @ disp[256][p''] + bp.
// Tile 96oc x 32px, thread tile 6oc x 2px, 2048 blocks = 8 blocks/CU
// (LDS 16.8KB, VGPR<=64 via launch_bounds(256,8) -> 32 waves/CU).
// blk&7 = f1 = K1 writer's XCD for this px range.
__global__ __launch_bounds__(TPB, 8)
void cc_proj(const float* __restrict__ disp, const float* __restrict__ Wp,
             const float* __restrict__ bp, float* __restrict__ out)
{
    __shared__ __align__(16) float wch[3200];    // [32k][100] (oc, pad 100)
    __shared__ __align__(16) float xch[1024];    // [32k][32px]
    const int t   = threadIdx.x;
    const int toc = t >> 4;           // 0..15: oc-group (6 oc)
    const int tp  = t & 15;           // px-group (2 consecutive px)
    const int blk = blockIdx.x;       // 0..2047
    const int f1   = blk & 7;         // XCD-matched to K1 writer
    const int half = (blk >> 3) & 1;
    const int f2   = (blk >> 4) & 7;
    const int bb   = blk >> 7;
    const int fold = f1*8 + f2;
    const int pxbase = bb*4096 + fold*64 + half*32;

    float acc[6][2];
    #pragma unroll
    for (int o = 0; o < 6; ++o) {
        float b = bp[toc*6 + o];
        acc[o][0] = b; acc[o][1] = b;
    }

    // staging decode. W: 768 float4/chunk, 3/thread; oc consecutive per
    // store instr -> ~2-way banks (free). X: 256 float4/chunk, 1/thread.
    int woffg[3], wdst[3];
    #pragma unroll
    for (int i = 0; i < 3; ++i) {
        int fl = i*256 + t;           // 0..767
        int oc2 = fl % 96, kq = fl / 96;
        woffg[i] = oc2*256 + kq*4;
        wdst[i]  = (kq*4)*100 + oc2;
    }
    const int xoffg = (t >> 3)*65536 + pxbase + (t & 7)*4;
    const int xdst  = (t >> 3)*32 + (t & 7)*4;

    float4 pwr[3], pxr;
    #pragma unroll
    for (int i = 0; i < 3; ++i) pwr[i] = *(const float4*)(Wp + woffg[i]);
    pxr = *(const float4*)(disp + xoffg);
    #pragma unroll
    for (int i = 0; i < 3; ++i) {
        wch[wdst[i]      ] = pwr[i].x; wch[wdst[i] + 100] = pwr[i].y;
        wch[wdst[i] + 200] = pwr[i].z; wch[wdst[i] + 300] = pwr[i].w;
    }
    *(float4*)&xch[xdst] = pxr;
    __syncthreads();

    for (int kc = 0; ; ) {
        if (kc < 224) {
            #pragma unroll
            for (int i = 0; i < 3; ++i)
                pwr[i] = *(const float4*)(Wp + woffg[i] + kc + 32);
            pxr = *(const float4*)(disp + xoffg + (size_t)(kc+32)*65536);
        }
        #pragma unroll 4
        for (int k = 0; k < 32; ++k) {
            float2 wA = *(const float2*)&wch[k*100 + toc*6];
            float2 wB = *(const float2*)&wch[k*100 + toc*6 + 2];
            float2 wC = *(const float2*)&wch[k*100 + toc*6 + 4];
            float2 xv = *(const float2*)&xch[k*32 + tp*2];
            acc[0][0] = fmaf(wA.x, xv.x, acc[0][0]);
            acc[0][1] = fmaf(wA.x, xv.y, acc[0][1]);
            acc[1][0] = fmaf(wA.y, xv.x, acc[1][0]);
            acc[1][1] = fmaf(wA.y, xv.y, acc[1][1]);
            acc[2][0] = fmaf(wB.x, xv.x, acc[2][0]);
            acc[2][1] = fmaf(wB.x, xv.y, acc[2][1]);
            acc[3][0] = fmaf(wB.y, xv.x, acc[3][0]);
            acc[3][1] = fmaf(wB.y, xv.y, acc[3][1]);
            acc[4][0] = fmaf(wC.x, xv.x, acc[4][0]);
            acc[4][1] = fmaf(wC.x, xv.y, acc[4][1]);
            acc[5][0] = fmaf(wC.y, xv.x, acc[5][0]);
            acc[5][1] = fmaf(wC.y, xv.y, acc[5][1]);
        }
        if (kc == 224) break;
        __syncthreads();
        #pragma unroll
        for (int i = 0; i < 3; ++i) {
            wch[wdst[i]      ] = pwr[i].x; wch[wdst[i] + 100] = pwr[i].y;
            wch[wdst[i] + 200] = pwr[i].z; wch[wdst[i] + 300] = pwr[i].w;
        }
        *(float4*)&xch[xdst] = pxr;
        __syncthreads();
        kc += 32;
    }

    // epilogue: n = half*32 + tp*2 (even) -> two consecutive px same row
    const int n = half*32 + tp*2;
    const int r = n >> 3, hh = n & 7;
    size_t oaddr = (size_t)bb*96*4096 + (size_t)(toc*6)*4096
                 + (size_t)(f1*8 + r)*64 + f2*8 + hh;
    #pragma unroll
    for (int o = 0; o < 6; ++o) {
        float2 st; st.x = acc[o][0]; st.y = acc[o][1];
        *(float2*)&out[oaddr + (size_t)o*4096] = st;
    }
}

extern "C" void kernel_launch(void* const* d_in, const int* in_sizes, int n_in,
                              void* d_out, int out_size, void* d_ws, size_t ws_size,
                              hipStream_t stream) {
    (void)in_sizes; (void)n_in; (void)out_size; (void)ws_size;
    float* disp = (float*)d_ws;   // 256*65536 floats = 64 MiB, layout [ch][p'']
    cc_main<<<dim3(4096), dim3(TPB), 0, stream>>>(
        (const float*)d_in[0],  // x
        (const float*)d_in[1],  // Wf
        (const float*)d_in[2],  // bf
        (const float*)d_in[3],  // Wv
        (const float*)d_in[4],  // bv
        (const float*)d_in[7],  // sim_alpha
        (const float*)d_in[8],  // sim_beta
        disp);
    cc_proj<<<dim3(2048), dim3(TPB), 0, stream>>>(
        disp,
        (const float*)d_in[5],  // Wp
        (const float*)d_in[6],  // bp
        (float*)d_out);
}